// Round 9
// baseline (502.322 us; speedup 1.0000x reference)
//
#include <hip/hip_runtime.h>
#include <math.h>

#define LDIM 2048
#define DDIM 128
#define BDIM 16
#define FDIM 100
// Split-K bf16 GEMM: A' = [AH | AL | AH], B' = [BH | BH | BL], K = 384.
// Panel layout per (batch,row-panel): [48 koct][128 row][8 elems] bf16 -> 16KB-contiguous K-tiles.
#define PANEL_U16 (48 * 1024)
// conv-as-GEMM: K = 3*128 = 384, N = 112 (100 filters padded to 7 tiles of 16)
#define FPAD 112
#define CT 64            // t-rows per conv block

typedef unsigned short u16;
typedef __bf16 bf16x8 __attribute__((ext_vector_type(8)));
typedef float f32x4 __attribute__((ext_vector_type(4)));

__device__ inline unsigned f2bfu(float x) {  // fp32 -> bf16 bits, RNE
  unsigned u = __float_as_uint(x);
  return (u + 0x7FFFu + ((u >> 16) & 1u)) >> 16;
}
__device__ inline unsigned pk2(float a, float b) {
  return f2bfu(a) | (f2bfu(b) << 16);
}
__device__ inline float bfhi(float x) {  // value of the bf16 hi part
  return __uint_as_float(f2bfu(x) << 16);
}

__device__ inline void glds16(const u16* g, u16* l) {
  __builtin_amdgcn_global_load_lds(
      (const __attribute__((address_space(1))) void*)g,
      (__attribute__((address_space(3))) void*)l, 16, 0, 0);
}

__device__ inline void ins3(float w, int idx, float v[3], int id[3]) {
  if (w > v[2]) {
    if (w > v[0]) { v[2]=v[1]; id[2]=id[1]; v[1]=v[0]; id[1]=id[0]; v[0]=w; id[0]=idx; }
    else if (w > v[1]) { v[2]=v[1]; id[2]=id[1]; v[1]=w; id[1]=idx; }
    else { v[2]=w; id[2]=idx; }
  }
}

// Expand fp32 inputs into split-bf16 panel layout (hi/lo), both ctx and main.
__global__ __launch_bounds__(256) void split_convert(const float* __restrict__ ctx,
    const float* __restrict__ mn, u16* __restrict__ ctxS, u16* __restrict__ mnS) {
  const int b = blockIdx.y;
  const int rp = blockIdx.x & 15, og = blockIdx.x >> 4;  // og 0..7
  const int tid = threadIdx.x;
  const int row = tid & 127;
  const int o = og * 2 + (tid >> 7);                     // source k-octet 0..15
  const size_t srcOff = (((size_t)b * LDIM + rp * 128 + row) * DDIM + o * 8);
  const float4 c0 = *(const float4*)(ctx + srcOff);
  const float4 c1 = *(const float4*)(ctx + srcOff + 4);
  const float4 m0 = *(const float4*)(mn + srcOff);
  const float4 m1 = *(const float4*)(mn + srcOff + 4);
  uint4 chi = make_uint4(pk2(c0.x,c0.y), pk2(c0.z,c0.w), pk2(c1.x,c1.y), pk2(c1.z,c1.w));
  uint4 clo = make_uint4(pk2(c0.x-bfhi(c0.x), c0.y-bfhi(c0.y)),
                         pk2(c0.z-bfhi(c0.z), c0.w-bfhi(c0.w)),
                         pk2(c1.x-bfhi(c1.x), c1.y-bfhi(c1.y)),
                         pk2(c1.z-bfhi(c1.z), c1.w-bfhi(c1.w)));
  uint4 mhi = make_uint4(pk2(m0.x,m0.y), pk2(m0.z,m0.w), pk2(m1.x,m1.y), pk2(m1.z,m1.w));
  uint4 mlo = make_uint4(pk2(m0.x-bfhi(m0.x), m0.y-bfhi(m0.y)),
                         pk2(m0.z-bfhi(m0.z), m0.w-bfhi(m0.w)),
                         pk2(m1.x-bfhi(m1.x), m1.y-bfhi(m1.y)),
                         pk2(m1.z-bfhi(m1.z), m1.w-bfhi(m1.w)));
  u16* dA = ctxS + ((size_t)b * 16 + rp) * PANEL_U16;
  u16* dB = mnS  + ((size_t)b * 16 + rp) * PANEL_U16;
  const int base = o * 1024 + row * 8;
  *(uint4*)(dA + base)         = chi;   // koct o      : AH
  *(uint4*)(dA + base + 16384) = clo;   // koct o + 16 : AL
  *(uint4*)(dA + base + 32768) = chi;   // koct o + 32 : AH
  *(uint4*)(dB + base)         = mhi;   // koct o      : BH
  *(uint4*)(dB + base + 16384) = mhi;   // koct o + 16 : BH
  *(uint4*)(dB + base + 32768) = mlo;   // koct o + 32 : BL
}

// W[b][c][m] = sum_k A'[c][k]*B'[m][k] over K=384 bf16 (== fp32 ctx.main^T to ~1e-4).
// 128x128 tile, 4 waves of 64x64, 16x16x32 bf16 MFMA, BK=64, global_load_lds staging.
__global__ __launch_bounds__(256) void gemm_mfma(const u16* __restrict__ A,
    const u16* __restrict__ B, float* __restrict__ W) {
  __shared__ u16 As[8192];   // 8 kocts x 128 rows x 8 elems = 16 KB
  __shared__ u16 Bs[8192];
  const int b = blockIdx.z;
  const int rp = blockIdx.y, mp = blockIdx.x;
  const int tid = threadIdx.x;
  const int w = tid >> 6, lane = tid & 63;
  const int lr = lane & 15, lg = lane >> 4;
  const int wr = w >> 1, wc = w & 1;
  const u16* srcA = A + ((size_t)b * 16 + rp) * PANEL_U16;
  const u16* srcB = B + ((size_t)b * 16 + mp) * PANEL_U16;
  f32x4 acc[4][4];
  const f32x4 zz = {0.f, 0.f, 0.f, 0.f};
  #pragma unroll
  for (int i = 0; i < 4; i++)
    #pragma unroll
    for (int j = 0; j < 4; j++) acc[i][j] = zz;

  for (int kt = 0; kt < 6; kt++) {
    if (kt) __syncthreads();
    const u16* sA = srcA + kt * 8192;
    const u16* sB = srcB + kt * 8192;
    #pragma unroll
    for (int q = 0; q < 4; q++) {
      const int c = q * 256 + w * 64;           // chunk index base for this wave
      glds16(sA + (size_t)(c + lane) * 8, (u16*)As + c * 8);
      glds16(sB + (size_t)(c + lane) * 8, (u16*)Bs + c * 8);
    }
    __syncthreads();
    #pragma unroll
    for (int ks = 0; ks < 2; ks++) {
      const int ab = (ks * 4 + lg) * 1024 + (wr * 64 + lr) * 8;
      const int bb = (ks * 4 + lg) * 1024 + (wc * 64 + lr) * 8;
      bf16x8 av[4], bv[4];
      #pragma unroll
      for (int i = 0; i < 4; i++) av[i] = *(const bf16x8*)&As[ab + i * 128];
      #pragma unroll
      for (int j = 0; j < 4; j++) bv[j] = *(const bf16x8*)&Bs[bb + j * 128];
      #pragma unroll
      for (int i = 0; i < 4; i++)
        #pragma unroll
        for (int j = 0; j < 4; j++)
          acc[i][j] = __builtin_amdgcn_mfma_f32_16x16x32_bf16(av[i], bv[j], acc[i][j], 0, 0, 0);
    }
  }
  // C/D layout (m89): col = lane&15, row = (lane>>4)*4 + reg
  float* Wb = W + (size_t)b * LDIM * LDIM + ((size_t)(rp * 128 + wr * 64)) * LDIM + mp * 128 + wc * 64;
  #pragma unroll
  for (int i = 0; i < 4; i++) {
    #pragma unroll
    for (int r = 0; r < 4; r++) {
      float* dst = Wb + (size_t)(i * 16 + lg * 4 + r) * LDIM + lr;
      #pragma unroll
      for (int j = 0; j < 4; j++) dst[j * 16] = acc[i][j][r];
    }
  }
}

// Per row r: top-3 (val,idx) over m, sum, sumsq -> normalized top-3 weights + std.
// One WAVE per row (4 rows/block): 8 coalesced float4 per lane held in registers,
// then 2-level serial LDS merge (64 -> 8 -> 1 records, 2 barriers). No shuffles.
__global__ __launch_bounds__(256) void row_stats(const float* __restrict__ W,
    float* __restrict__ rw, int* __restrict__ ri, float* __restrict__ rs) {
  const int b = blockIdx.y;
  const int wid = threadIdx.x >> 6, lane = threadIdx.x & 63;
  const int r = blockIdx.x * 4 + wid;
  const float4* row4 = (const float4*)(W + ((size_t)b*LDIM + r)*LDIM);
  float v[3] = {-3e38f,-3e38f,-3e38f}; int id[3] = {-1,-1,-1};
  float sum = 0.f, sq = 0.f;
  #pragma unroll
  for (int i = 0; i < 8; i++) {
    const int q = lane + 64*i;
    float4 w4 = row4[q];
    int m0 = q*4;
    sum += w4.x + w4.y + w4.z + w4.w;
    sq  += w4.x*w4.x + w4.y*w4.y + w4.z*w4.z + w4.w*w4.w;
    ins3(w4.x, m0+0, v, id);
    ins3(w4.y, m0+1, v, id);
    ins3(w4.z, m0+2, v, id);
    ins3(w4.w, m0+3, v, id);
  }
  __shared__ float sv[4][64][5];
  __shared__ int   si[4][64][3];
  __shared__ float sv2[4][8][5];
  __shared__ int   si2[4][8][3];
  sv[wid][lane][0]=v[0]; sv[wid][lane][1]=v[1]; sv[wid][lane][2]=v[2];
  sv[wid][lane][3]=sum;  sv[wid][lane][4]=sq;
  si[wid][lane][0]=id[0]; si[wid][lane][1]=id[1]; si[wid][lane][2]=id[2];
  __syncthreads();
  if (lane < 8) {
    float mv[3] = {-3e38f,-3e38f,-3e38f}; int mi[3] = {-1,-1,-1};
    float ms = 0.f, mq = 0.f;
    #pragma unroll
    for (int t = 0; t < 8; t++) {
      int o = lane*8 + t;
      ins3(sv[wid][o][0], si[wid][o][0], mv, mi);
      ins3(sv[wid][o][1], si[wid][o][1], mv, mi);
      ins3(sv[wid][o][2], si[wid][o][2], mv, mi);
      ms += sv[wid][o][3]; mq += sv[wid][o][4];
    }
    sv2[wid][lane][0]=mv[0]; sv2[wid][lane][1]=mv[1]; sv2[wid][lane][2]=mv[2];
    sv2[wid][lane][3]=ms; sv2[wid][lane][4]=mq;
    si2[wid][lane][0]=mi[0]; si2[wid][lane][1]=mi[1]; si2[wid][lane][2]=mi[2];
  }
  __syncthreads();
  if (lane == 0) {
    float mv[3] = {-3e38f,-3e38f,-3e38f}; int mi[3] = {-1,-1,-1};
    float ms = 0.f, mq = 0.f;
    #pragma unroll
    for (int t = 0; t < 8; t++) {
      ins3(sv2[wid][t][0], si2[wid][t][0], mv, mi);
      ins3(sv2[wid][t][1], si2[wid][t][1], mv, mi);
      ins3(sv2[wid][t][2], si2[wid][t][2], mv, mi);
      ms += sv2[wid][t][3]; mq += sv2[wid][t][4];
    }
    float inv = 1.f/(mv[0]+mv[1]+mv[2]);
    size_t base = (size_t)b*LDIM + r;
    rw[base*3+0]=mv[0]*inv; rw[base*3+1]=mv[1]*inv; rw[base*3+2]=mv[2]*inv;
    ri[base*3+0]=mi[0]; ri[base*3+1]=mi[1]; ri[base*3+2]=mi[2];
    float mean = ms * (1.f/LDIM);
    float var = mq*(1.f/LDIM) - mean*mean;
    rs[base] = sqrtf(fmaxf(var, 0.f));
  }
}

// Per-column partial stats over a 32-row block. Each thread owns FOUR adjacent
// columns via float4 loads (1 KB/wave-instr, the coalescing sweet spot).
// Grid (2, 64, nb); records 64 per column; writes 128 consecutive B/thread.
__global__ __launch_bounds__(256) void col_part(const float* __restrict__ W,
    unsigned* __restrict__ colP) {
  const int cp = blockIdx.x, rb = blockIdx.y, b = blockIdx.z;
  const int t = threadIdx.x;
  const float* Wb = W + (size_t)b*LDIM*LDIM;
  const int c0 = cp*1024 + t*4;
  float v[4][3]; int id[4][3]; float sm[4], s2[4];
  #pragma unroll
  for (int s = 0; s < 4; s++) {
    v[s][0]=-3e38f; v[s][1]=-3e38f; v[s][2]=-3e38f;
    id[s][0]=-1; id[s][1]=-1; id[s][2]=-1;
    sm[s]=0.f; s2[s]=0.f;
  }
  #pragma unroll 8
  for (int r = 0; r < 32; r++) {
    const int row = rb*32 + r;
    const float4 w4 = *(const float4*)&Wb[(size_t)row*LDIM + c0];
    sm[0] += w4.x; s2[0] += w4.x*w4.x; ins3(w4.x, row, v[0], id[0]);
    sm[1] += w4.y; s2[1] += w4.y*w4.y; ins3(w4.y, row, v[1], id[1]);
    sm[2] += w4.z; s2[2] += w4.z*w4.z; ins3(w4.z, row, v[2], id[2]);
    sm[3] += w4.w; s2[3] += w4.w*w4.w; ins3(w4.w, row, v[3], id[3]);
  }
  #pragma unroll
  for (int s = 0; s < 4; s++) {
    size_t rec = (((size_t)b*64 + rb)*LDIM + (c0 + s)) * 8;
    uint4 lo = make_uint4(__float_as_uint(v[s][0]), __float_as_uint(v[s][1]),
                          __float_as_uint(v[s][2]), __float_as_uint(sm[s]));
    uint4 hi = make_uint4(__float_as_uint(s2[s]), (unsigned)id[s][0],
                          (unsigned)id[s][1], (unsigned)id[s][2]);
    *(uint4*)(colP + rec)     = lo;
    *(uint4*)(colP + rec + 4) = hi;
  }
}

// Merge 64 per-row-block partials per column -> normalized top-3 weights + indices + std.
__global__ __launch_bounds__(256) void col_combine(const unsigned* __restrict__ P,
    float* __restrict__ w3, int* __restrict__ i3, float* __restrict__ sd) {
  const int b = blockIdx.y;
  const int c = blockIdx.x * 256 + threadIdx.x;
  float v[3] = {-3e38f,-3e38f,-3e38f}; int id[3] = {-1,-1,-1};
  float sum = 0.f, sq = 0.f;
  #pragma unroll 4
  for (int t = 0; t < 64; t++) {
    const unsigned* rec = P + (((size_t)b*64 + t)*LDIM + c) * 8;
    const uint4 lo = *(const uint4*)rec;
    const uint4 hi = *(const uint4*)(rec + 4);
    ins3(__uint_as_float(lo.x), (int)hi.y, v, id);
    ins3(__uint_as_float(lo.y), (int)hi.z, v, id);
    ins3(__uint_as_float(lo.z), (int)hi.w, v, id);
    sum += __uint_as_float(lo.w); sq += __uint_as_float(hi.x);
  }
  float inv = 1.f/(v[0]+v[1]+v[2]);
  size_t o = (size_t)b*LDIM + c;
  w3[o*3+0]=v[0]*inv; w3[o*3+1]=v[1]*inv; w3[o*3+2]=v[2]*inv;
  i3[o*3+0]=id[0]; i3[o*3+1]=id[1]; i3[o*3+2]=id[2];
  float mean = sum * (1.f/LDIM);
  float var = sq*(1.f/LDIM) - mean*mean;
  sd[o] = sqrtf(fmaxf(var, 0.f));
}

// att_merge_c[m][d] += wk_c[c][m] * ctx[c][d]  -- 3 targets per row c (scatter).
__global__ __launch_bounds__(128) void scatter_att(const float* __restrict__ ctx,
    const float* __restrict__ rw, const int* __restrict__ ri,
    float* __restrict__ attC) {
  const int b = blockIdx.y, c = blockIdx.x, d = threadIdx.x;
  const size_t base = (size_t)b*LDIM + c;
  const float x = ctx[base*DDIM + d];
  #pragma unroll
  for (int t = 0; t < 3; t++) {
    float w = rw[base*3 + t];
    int m = ri[base*3 + t];
    atomicAdd(&attC[((size_t)b*LDIM + m)*DDIM + d], w*x);
  }
}

// outputs_c = |ctx - gather(col top-3 of main)| * row_std   -> bf16
// outputs_m = |main - attC| * col_std                       -> bf16
__global__ __launch_bounds__(128) void make_outputs(const float* __restrict__ ctx,
    const float* __restrict__ mn, const float* __restrict__ attC,
    const float* __restrict__ rs, const float* __restrict__ cw,
    const int* __restrict__ ci, const float* __restrict__ cs,
    u16* __restrict__ outCb, u16* __restrict__ outMb) {
  const int b = blockIdx.y, i = blockIdx.x, d = threadIdx.x;
  const size_t base = (size_t)b*LDIM + i;
  float am = 0.f;
  #pragma unroll
  for (int t = 0; t < 3; t++)
    am += cw[base*3+t] * mn[((size_t)b*LDIM + ci[base*3+t])*DDIM + d];
  float oc = fabsf(ctx[base*DDIM + d] - am) * rs[base];
  float om = fabsf(mn[base*DDIM + d] - attC[base*DDIM + d]) * cs[base];
  outCb[base*DDIM + d] = (u16)f2bfu(oc);
  outMb[base*DDIM + d] = (u16)f2bfu(om);
}

// Convert conv weights to bf16 panel wB[ko 0..47][f 0..111][e 0..7]:
// wB[ko][f][e] = w[ks = ko/16][d = (ko%16)*8 + e][f], f >= FDIM -> 0.
__global__ __launch_bounds__(256) void conv_prep_w(const float* __restrict__ wv,
    u16* __restrict__ wB) {
  int idx = blockIdx.x * 256 + threadIdx.x;
  if (idx >= 48 * FPAD * 8) return;
  int e = idx & 7, f = (idx >> 3) % FPAD, ko = idx / (FPAD * 8);
  int ks = ko >> 4, d = ((ko & 15) << 3) | e;
  float val = (f < FDIM) ? wv[(ks * DDIM + d) * FDIM + f] : 0.f;
  wB[idx] = (u16)f2bfu(val);
}

// conv1d(KS=3) + bias + relu + maxpool as MFMA GEMM: y[t,f] = sum_k X[t+ks,d]*w[ks,d,f].
// Block: 256 thr = 4 waves, covers CT=64 t-rows x all 112 f. K=384 -> 12 MFMA/f-tile.
// Fragment conventions identical to gemm_mfma (A row=lr, k-slice=lg*8; C row=lg*4+r, col=lr).
__global__ __launch_bounds__(256) void conv_mfma(const u16* __restrict__ XCb,
    const u16* __restrict__ XMb, const u16* __restrict__ wB,
    const float* __restrict__ bias, float* __restrict__ out) {
  const int b = blockIdx.y, z = blockIdx.z;
  const int t0 = blockIdx.x * CT;
  const u16* X = (z == 0 ? XCb : XMb) + (size_t)b * LDIM * DDIM;
  __shared__ u16 Xs[(CT + 2) * 128];   // rows of 256B, XOR-swizzled
  __shared__ float smax[FPAD];
  const int tid = threadIdx.x;
  for (int e = tid; e < (CT + 2) * 16; e += 256) {
    int row = e >> 4, c16 = e & 15;
    int t = t0 + row;
    uint4 val = (t < LDIM) ? *(const uint4*)&X[(size_t)t * DDIM + c16 * 8]
                           : make_uint4(0u, 0u, 0u, 0u);
    int byte = row * 256 + ((c16 * 16) ^ ((row & 7) << 4));
    *(uint4*)((char*)Xs + byte) = val;
  }
  if (tid < FPAD) smax[tid] = 0.f;
  __syncthreads();
  const int w = tid >> 6, lane = tid & 63;
  const int lr = lane & 15, lg = lane >> 4;
  const int lt0 = w * 16;
  bf16x8 av[12];
  #pragma unroll
  for (int kk = 0; kk < 12; kk++) {
    int ko = kk * 4 + lg;          // k-octet 0..47; k = ko*8+e
    int ks = ko >> 4, d8 = ko & 15;
    int row = lt0 + lr + ks;
    int byte = row * 256 + ((d8 * 16) ^ ((row & 7) << 4));
    av[kk] = *(const bf16x8*)((const char*)Xs + byte);
  }
  for (int ft = 0; ft < 7; ft++) {
    f32x4 acc = {0.f, 0.f, 0.f, 0.f};
    #pragma unroll
    for (int kk = 0; kk < 12; kk++) {
      int ko = kk * 4 + lg;
      bf16x8 bv = *(const bf16x8*)&wB[((size_t)ko * FPAD + ft * 16 + lr) * 8];
      acc = __builtin_amdgcn_mfma_f32_16x16x32_bf16(av[kk], bv, acc, 0, 0, 0);
    }
    int f = ft * 16 + lr;
    float bb = (f < FDIM) ? bias[f] : 0.f;
    float mx = 0.f;
    #pragma unroll
    for (int r = 0; r < 4; r++) {
      int t = t0 + lt0 + lg * 4 + r;
      float y = fmaxf(acc[r] + bb, 0.f);
      if (t <= LDIM - 3) mx = fmaxf(mx, y);   // invalid t -> 0 (safe: relu-max >= 0)
    }
    mx = fmaxf(mx, __shfl_xor(mx, 16));
    mx = fmaxf(mx, __shfl_xor(mx, 32));
    if (lg == 0 && f < FDIM)
      atomicMax((unsigned*)&smax[f], __float_as_uint(mx));
  }
  __syncthreads();
  if (tid < FDIM)
    atomicMax((unsigned*)&out[(size_t)b * (2 * FDIM) + z * FDIM + tid],
              __float_as_uint(smax[tid]));
}

extern "C" void kernel_launch(void* const* d_in, const int* in_sizes, int n_in,
                              void* d_out, int out_size, void* d_ws, size_t ws_size,
                              hipStream_t stream) {
  const float* ctx   = (const float*)d_in[0];
  const float* mn    = (const float*)d_in[1];
  const float* wconv = (const float*)d_in[2];
  const float* bias  = (const float*)d_in[3];
  float* out = (float*)d_out;

  // pool accumulators must start at 0 (d_out is poisoned before every call)
  hipMemsetAsync(d_out, 0, sizeof(float)*(size_t)out_size, stream);

  // Workspace: [wB bf16 weight panel: 64K floats reserved] then per-iteration arrays.
  const size_t wbFloats = 65536;
  // Per-batch (floats/dwords):
  //   W:                    L*L        = 4194304
  //   col partial records:  64*L*8     = 1048576
  //   final stats:          14*L       = 28672
  //   attC:                 L*D        = 262144
  //   outCb+outMb (u16):    2*L*D u16  = 262144 float-equiv
  //   split-bf16 panels:    2*16*PANEL_U16/2 = 786432
  const size_t perBatchFloats = (size_t)LDIM*LDIM + (size_t)64*LDIM*8 + 14*(size_t)LDIM
                              + (size_t)LDIM*DDIM + (size_t)LDIM*DDIM
                              + 2*(size_t)16*PANEL_U16/2;
  const size_t perBatchBytes = perBatchFloats * sizeof(float);
  int nbMax = (int)((ws_size - wbFloats*sizeof(float)) / perBatchBytes);
  if (nbMax < 1) nbMax = 1;
  if (nbMax > BDIM) nbMax = BDIM;

  u16* wB = (u16*)d_ws;
  float* iterBase = (float*)d_ws + wbFloats;
  conv_prep_w<<<dim3((48*FPAD*8 + 255)/256), 256, 0, stream>>>(wconv, wB);

  for (int b0 = 0; b0 < BDIM; b0 += nbMax) {
    const int nb = (BDIM - b0 < nbMax) ? (BDIM - b0) : nbMax;
    float* Wbuf = iterBase;
    unsigned* colP = (unsigned*)(Wbuf + (size_t)nb*LDIM*LDIM);
    float* rowW = (float*)(colP + (size_t)nb*64*LDIM*8);
    int*   rowI = (int*)(rowW + (size_t)nb*LDIM*3);
    float* rowS = (float*)(rowI + (size_t)nb*LDIM*3);
    float* colW = rowS + (size_t)nb*LDIM;
    int*   colI = (int*)(colW + (size_t)nb*LDIM*3);
    float* colS = (float*)(colI + (size_t)nb*LDIM*3);
    float* attC = colS + (size_t)nb*LDIM;
    u16*   outCb = (u16*)(attC + (size_t)nb*LDIM*DDIM);
    u16*   outMb = outCb + (size_t)nb*LDIM*DDIM;
    u16*   ctxS = outMb + (size_t)nb*LDIM*DDIM;
    u16*   mnS  = ctxS + (size_t)nb*16*PANEL_U16;
    const float* ctxb = ctx + (size_t)b0*LDIM*DDIM;
    const float* mnb  = mn  + (size_t)b0*LDIM*DDIM;

    split_convert<<<dim3(128, nb), 256, 0, stream>>>(ctxb, mnb, ctxS, mnS);
    gemm_mfma<<<dim3(LDIM/128, LDIM/128, nb), 256, 0, stream>>>(ctxS, mnS, Wbuf);
    row_stats<<<dim3(LDIM/4, nb), 256, 0, stream>>>(Wbuf, rowW, rowI, rowS);
    col_part<<<dim3(2, 64, nb), 256, 0, stream>>>(Wbuf, colP);
    col_combine<<<dim3(LDIM/256, nb), 256, 0, stream>>>(colP, colW, colI, colS);
    hipMemsetAsync(attC, 0, (size_t)nb*LDIM*DDIM*sizeof(float), stream);
    scatter_att<<<dim3(LDIM, nb), 128, 0, stream>>>(ctxb, rowW, rowI, attC);
    make_outputs<<<dim3(LDIM, nb), 128, 0, stream>>>(ctxb, mnb, attC, rowS, colW, colI, colS, outCb, outMb);
    conv_mfma<<<dim3(LDIM/CT, nb, 2), 256, 0, stream>>>(
        outCb, outMb, wB, bias, out + (size_t)b0*2*FDIM);
  }
}

// Round 11
// 470.820 us; speedup vs baseline: 1.0669x; 1.0669x over previous
//
#include <hip/hip_runtime.h>
#include <math.h>

#define LDIM 2048
#define DDIM 128
#define BDIM 16
#define FDIM 100
// Split-K bf16 GEMM: A' = [AH | AL | AH], B' = [BH | BH | BL], K = 384.
// Panel layout per (batch,row-panel): [48 koct][128 row][8 elems] bf16 -> 16KB-contiguous K-tiles.
#define PANEL_U16 (48 * 1024)
// conv-as-GEMM: K = 3*128 = 384, N = 112 (100 filters padded to 7 tiles of 16)
#define FPAD 112
#define CT 64            // t-rows per conv block

typedef unsigned short u16;
typedef __bf16 bf16x8 __attribute__((ext_vector_type(8)));
typedef float f32x4 __attribute__((ext_vector_type(4)));

__device__ inline unsigned f2bfu(float x) {  // fp32 -> bf16 bits, RNE
  unsigned u = __float_as_uint(x);
  return (u + 0x7FFFu + ((u >> 16) & 1u)) >> 16;
}
__device__ inline unsigned pk2(float a, float b) {
  return f2bfu(a) | (f2bfu(b) << 16);
}
__device__ inline float bfhi(float x) {  // value of the bf16 hi part
  return __uint_as_float(f2bfu(x) << 16);
}

__device__ inline void glds16(const u16* g, u16* l) {
  __builtin_amdgcn_global_load_lds(
      (const __attribute__((address_space(1))) void*)g,
      (__attribute__((address_space(3))) void*)l, 16, 0, 0);
}

__device__ inline void ins3(float w, int idx, float v[3], int id[3]) {
  if (w > v[2]) {
    if (w > v[0]) { v[2]=v[1]; id[2]=id[1]; v[1]=v[0]; id[1]=id[0]; v[0]=w; id[0]=idx; }
    else if (w > v[1]) { v[2]=v[1]; id[2]=id[1]; v[1]=w; id[1]=idx; }
    else { v[2]=w; id[2]=idx; }
  }
}

// Expand fp32 inputs into split-bf16 panel layout (hi/lo), both ctx and main.
__global__ __launch_bounds__(256) void split_convert(const float* __restrict__ ctx,
    const float* __restrict__ mn, u16* __restrict__ ctxS, u16* __restrict__ mnS) {
  const int b = blockIdx.y;
  const int rp = blockIdx.x & 15, og = blockIdx.x >> 4;  // og 0..7
  const int tid = threadIdx.x;
  const int row = tid & 127;
  const int o = og * 2 + (tid >> 7);                     // source k-octet 0..15
  const size_t srcOff = (((size_t)b * LDIM + rp * 128 + row) * DDIM + o * 8);
  const float4 c0 = *(const float4*)(ctx + srcOff);
  const float4 c1 = *(const float4*)(ctx + srcOff + 4);
  const float4 m0 = *(const float4*)(mn + srcOff);
  const float4 m1 = *(const float4*)(mn + srcOff + 4);
  uint4 chi = make_uint4(pk2(c0.x,c0.y), pk2(c0.z,c0.w), pk2(c1.x,c1.y), pk2(c1.z,c1.w));
  uint4 clo = make_uint4(pk2(c0.x-bfhi(c0.x), c0.y-bfhi(c0.y)),
                         pk2(c0.z-bfhi(c0.z), c0.w-bfhi(c0.w)),
                         pk2(c1.x-bfhi(c1.x), c1.y-bfhi(c1.y)),
                         pk2(c1.z-bfhi(c1.z), c1.w-bfhi(c1.w)));
  uint4 mhi = make_uint4(pk2(m0.x,m0.y), pk2(m0.z,m0.w), pk2(m1.x,m1.y), pk2(m1.z,m1.w));
  uint4 mlo = make_uint4(pk2(m0.x-bfhi(m0.x), m0.y-bfhi(m0.y)),
                         pk2(m0.z-bfhi(m0.z), m0.w-bfhi(m0.w)),
                         pk2(m1.x-bfhi(m1.x), m1.y-bfhi(m1.y)),
                         pk2(m1.z-bfhi(m1.z), m1.w-bfhi(m1.w)));
  u16* dA = ctxS + ((size_t)b * 16 + rp) * PANEL_U16;
  u16* dB = mnS  + ((size_t)b * 16 + rp) * PANEL_U16;
  const int base = o * 1024 + row * 8;
  *(uint4*)(dA + base)         = chi;   // koct o      : AH
  *(uint4*)(dA + base + 16384) = clo;   // koct o + 16 : AL
  *(uint4*)(dA + base + 32768) = chi;   // koct o + 32 : AH
  *(uint4*)(dB + base)         = mhi;   // koct o      : BH
  *(uint4*)(dB + base + 16384) = mhi;   // koct o + 16 : BH
  *(uint4*)(dB + base + 32768) = mlo;   // koct o + 32 : BL
}

// W[b][c][m] = sum_k A'[c][k]*B'[m][k] over K=384 bf16 (== fp32 ctx.main^T to ~1e-4).
// 128x128 tile, 4 waves of 64x64, 16x16x32 bf16 MFMA, BK=64, global_load_lds staging.
// W stored fp32 (fp16 breaks top-3 index selection -- R10 failure).
__global__ __launch_bounds__(256) void gemm_mfma(const u16* __restrict__ A,
    const u16* __restrict__ B, float* __restrict__ W) {
  __shared__ u16 As[8192];   // 8 kocts x 128 rows x 8 elems = 16 KB
  __shared__ u16 Bs[8192];
  const int b = blockIdx.z;
  const int rp = blockIdx.y, mp = blockIdx.x;
  const int tid = threadIdx.x;
  const int w = tid >> 6, lane = tid & 63;
  const int lr = lane & 15, lg = lane >> 4;
  const int wr = w >> 1, wc = w & 1;
  const u16* srcA = A + ((size_t)b * 16 + rp) * PANEL_U16;
  const u16* srcB = B + ((size_t)b * 16 + mp) * PANEL_U16;
  f32x4 acc[4][4];
  const f32x4 zz = {0.f, 0.f, 0.f, 0.f};
  #pragma unroll
  for (int i = 0; i < 4; i++)
    #pragma unroll
    for (int j = 0; j < 4; j++) acc[i][j] = zz;

  for (int kt = 0; kt < 6; kt++) {
    if (kt) __syncthreads();
    const u16* sA = srcA + kt * 8192;
    const u16* sB = srcB + kt * 8192;
    #pragma unroll
    for (int q = 0; q < 4; q++) {
      const int c = q * 256 + w * 64;           // chunk index base for this wave
      glds16(sA + (size_t)(c + lane) * 8, (u16*)As + c * 8);
      glds16(sB + (size_t)(c + lane) * 8, (u16*)Bs + c * 8);
    }
    __syncthreads();
    #pragma unroll
    for (int ks = 0; ks < 2; ks++) {
      const int ab = (ks * 4 + lg) * 1024 + (wr * 64 + lr) * 8;
      const int bb = (ks * 4 + lg) * 1024 + (wc * 64 + lr) * 8;
      bf16x8 av[4], bv[4];
      #pragma unroll
      for (int i = 0; i < 4; i++) av[i] = *(const bf16x8*)&As[ab + i * 128];
      #pragma unroll
      for (int j = 0; j < 4; j++) bv[j] = *(const bf16x8*)&Bs[bb + j * 128];
      #pragma unroll
      for (int i = 0; i < 4; i++)
        #pragma unroll
        for (int j = 0; j < 4; j++)
          acc[i][j] = __builtin_amdgcn_mfma_f32_16x16x32_bf16(av[i], bv[j], acc[i][j], 0, 0, 0);
    }
  }
  // C/D layout (m89): col = lane&15, row = (lane>>4)*4 + reg
  float* Wb = W + (size_t)b * LDIM * LDIM + ((size_t)(rp * 128 + wr * 64)) * LDIM + mp * 128 + wc * 64;
  #pragma unroll
  for (int i = 0; i < 4; i++) {
    #pragma unroll
    for (int r = 0; r < 4; r++) {
      float* dst = Wb + (size_t)(i * 16 + lg * 4 + r) * LDIM + lr;
      #pragma unroll
      for (int j = 0; j < 4; j++) dst[j * 16] = acc[i][j][r];
    }
  }
}

// Fused row+col stats: ONE pass over W. Per 64x256 tile (LDS-staged):
//   col partials: thread-per-column over 64 rows  -> colP (32 records/col, R8 format)
//   row partials: 4 threads/row over 64-col quarters, serial LDS merge -> rowP (8 records/row)
// No shuffles anywhere. Grid (8, 32, nb).
__global__ __launch_bounds__(256) void fused_stats(const float* __restrict__ W,
    unsigned* __restrict__ rowP, unsigned* __restrict__ colP) {
  __shared__ float tile[64 * 260];       // pad 260: col walk bank-free, row walk 8-way
  __shared__ float qv[64][4][5];
  __shared__ int   qi[64][4][3];
  const int cp = blockIdx.x, rb = blockIdx.y, b = blockIdx.z;
  const int tid = threadIdx.x;
  const float* Wb = W + (size_t)b*LDIM*LDIM;
  // Phase 1: load 64x256 tile, coalesced float4 (wave covers one 1KB row-segment).
  float4 tmp[16];
  const int rr = tid >> 6, c4 = tid & 63;
  #pragma unroll
  for (int g = 0; g < 16; g++) {
    int r = g*4 + rr;
    tmp[g] = *(const float4*)&Wb[(size_t)(rb*64 + r)*LDIM + cp*256 + c4*4];
  }
  #pragma unroll
  for (int g = 0; g < 16; g++) {
    int r = g*4 + rr;
    *(float4*)&tile[r*260 + c4*4] = tmp[g];
  }
  __syncthreads();
  // Phase 2: col partials (thread t owns column cp*256+t).
  {
    float v[3] = {-3e38f,-3e38f,-3e38f}; int id[3] = {-1,-1,-1};
    float sm = 0.f, s2 = 0.f;
    #pragma unroll 8
    for (int r = 0; r < 64; r++) {
      float w = tile[r*260 + tid];
      sm += w; s2 += w*w; ins3(w, rb*64 + r, v, id);
    }
    size_t rec = (((size_t)b*32 + rb)*LDIM + cp*256 + tid) * 8;
    uint4 lo = make_uint4(__float_as_uint(v[0]), __float_as_uint(v[1]),
                          __float_as_uint(v[2]), __float_as_uint(sm));
    uint4 hi = make_uint4(__float_as_uint(s2), (unsigned)id[0],
                          (unsigned)id[1], (unsigned)id[2]);
    *(uint4*)(colP + rec)     = lo;
    *(uint4*)(colP + rec + 4) = hi;
  }
  // Phase 3: row quarter-partials (thread t -> row t>>2, quarter t&3).
  {
    const int row8 = tid >> 2, q = tid & 3;
    float v[3] = {-3e38f,-3e38f,-3e38f}; int id[3] = {-1,-1,-1};
    float sm = 0.f, s2 = 0.f;
    #pragma unroll 8
    for (int k = 0; k < 64; k++) {
      float w = tile[row8*260 + q*64 + k];
      sm += w; s2 += w*w; ins3(w, cp*256 + q*64 + k, v, id);
    }
    qv[row8][q][0]=v[0]; qv[row8][q][1]=v[1]; qv[row8][q][2]=v[2];
    qv[row8][q][3]=sm;   qv[row8][q][4]=s2;
    qi[row8][q][0]=id[0]; qi[row8][q][1]=id[1]; qi[row8][q][2]=id[2];
  }
  __syncthreads();
  if (tid < 64) {
    float v[3] = {-3e38f,-3e38f,-3e38f}; int id[3] = {-1,-1,-1};
    float sm = 0.f, s2 = 0.f;
    #pragma unroll
    for (int q = 0; q < 4; q++) {
      ins3(qv[tid][q][0], qi[tid][q][0], v, id);
      ins3(qv[tid][q][1], qi[tid][q][1], v, id);
      ins3(qv[tid][q][2], qi[tid][q][2], v, id);
      sm += qv[tid][q][3]; s2 += qv[tid][q][4];
    }
    size_t rec = (((size_t)b*8 + cp)*LDIM + rb*64 + tid) * 8;
    uint4 lo = make_uint4(__float_as_uint(v[0]), __float_as_uint(v[1]),
                          __float_as_uint(v[2]), __float_as_uint(sm));
    uint4 hi = make_uint4(__float_as_uint(s2), (unsigned)id[0],
                          (unsigned)id[1], (unsigned)id[2]);
    *(uint4*)(rowP + rec)     = lo;
    *(uint4*)(rowP + rec + 4) = hi;
  }
}

// Merge nt per-tile partials per index -> normalized top-3 weights + indices + std.
__global__ __launch_bounds__(256) void stats_combine(const unsigned* __restrict__ P,
    int nt, float* __restrict__ w3, int* __restrict__ i3, float* __restrict__ sd) {
  const int b = blockIdx.y;
  const int c = blockIdx.x * 256 + threadIdx.x;
  float v[3] = {-3e38f,-3e38f,-3e38f}; int id[3] = {-1,-1,-1};
  float sum = 0.f, sq = 0.f;
  for (int t = 0; t < nt; t++) {
    const unsigned* rec = P + (((size_t)b*nt + t)*LDIM + c) * 8;
    const uint4 lo = *(const uint4*)rec;
    const uint4 hi = *(const uint4*)(rec + 4);
    ins3(__uint_as_float(lo.x), (int)hi.y, v, id);
    ins3(__uint_as_float(lo.y), (int)hi.z, v, id);
    ins3(__uint_as_float(lo.z), (int)hi.w, v, id);
    sum += __uint_as_float(lo.w); sq += __uint_as_float(hi.x);
  }
  float inv = 1.f/(v[0]+v[1]+v[2]);
  size_t o = (size_t)b*LDIM + c;
  w3[o*3+0]=v[0]*inv; w3[o*3+1]=v[1]*inv; w3[o*3+2]=v[2]*inv;
  i3[o*3+0]=id[0]; i3[o*3+1]=id[1]; i3[o*3+2]=id[2];
  float mean = sum * (1.f/LDIM);
  float var = sq*(1.f/LDIM) - mean*mean;
  sd[o] = sqrtf(fmaxf(var, 0.f));
}

// att_merge_c[m][d] += wk_c[c][m] * ctx[c][d]  -- 3 targets per row c (scatter).
__global__ __launch_bounds__(128) void scatter_att(const float* __restrict__ ctx,
    const float* __restrict__ rw, const int* __restrict__ ri,
    float* __restrict__ attC) {
  const int b = blockIdx.y, c = blockIdx.x, d = threadIdx.x;
  const size_t base = (size_t)b*LDIM + c;
  const float x = ctx[base*DDIM + d];
  #pragma unroll
  for (int t = 0; t < 3; t++) {
    float w = rw[base*3 + t];
    int m = ri[base*3 + t];
    atomicAdd(&attC[((size_t)b*LDIM + m)*DDIM + d], w*x);
  }
}

// outputs_c = |ctx - gather(col top-3 of main)| * row_std   -> bf16
// outputs_m = |main - attC| * col_std                       -> bf16
__global__ __launch_bounds__(128) void make_outputs(const float* __restrict__ ctx,
    const float* __restrict__ mn, const float* __restrict__ attC,
    const float* __restrict__ rs, const float* __restrict__ cw,
    const int* __restrict__ ci, const float* __restrict__ cs,
    u16* __restrict__ outCb, u16* __restrict__ outMb) {
  const int b = blockIdx.y, i = blockIdx.x, d = threadIdx.x;
  const size_t base = (size_t)b*LDIM + i;
  float am = 0.f;
  #pragma unroll
  for (int t = 0; t < 3; t++)
    am += cw[base*3+t] * mn[((size_t)b*LDIM + ci[base*3+t])*DDIM + d];
  float oc = fabsf(ctx[base*DDIM + d] - am) * rs[base];
  float om = fabsf(mn[base*DDIM + d] - attC[base*DDIM + d]) * cs[base];
  outCb[base*DDIM + d] = (u16)f2bfu(oc);
  outMb[base*DDIM + d] = (u16)f2bfu(om);
}

// Convert conv weights to bf16 panel wB[ko 0..47][f 0..111][e 0..7]:
// wB[ko][f][e] = w[ks = ko/16][d = (ko%16)*8 + e][f], f >= FDIM -> 0.
__global__ __launch_bounds__(256) void conv_prep_w(const float* __restrict__ wv,
    u16* __restrict__ wB) {
  int idx = blockIdx.x * 256 + threadIdx.x;
  if (idx >= 48 * FPAD * 8) return;
  int e = idx & 7, f = (idx >> 3) % FPAD, ko = idx / (FPAD * 8);
  int ks = ko >> 4, d = ((ko & 15) << 3) | e;
  float val = (f < FDIM) ? wv[(ks * DDIM + d) * FDIM + f] : 0.f;
  wB[idx] = (u16)f2bfu(val);
}

// conv1d(KS=3) + bias + relu + maxpool as MFMA GEMM: y[t,f] = sum_k X[t+ks,d]*w[ks,d,f].
// Block: 256 thr = 4 waves, covers CT=64 t-rows x all 112 f. K=384 -> 12 MFMA/f-tile.
// Fragment conventions identical to gemm_mfma (A row=lr, k-slice=lg*8; C row=lg*4+r, col=lr).
__global__ __launch_bounds__(256) void conv_mfma(const u16* __restrict__ XCb,
    const u16* __restrict__ XMb, const u16* __restrict__ wB,
    const float* __restrict__ bias, float* __restrict__ out) {
  const int b = blockIdx.y, z = blockIdx.z;
  const int t0 = blockIdx.x * CT;
  const u16* X = (z == 0 ? XCb : XMb) + (size_t)b * LDIM * DDIM;
  __shared__ u16 Xs[(CT + 2) * 128];   // rows of 256B, XOR-swizzled
  __shared__ float smax[FPAD];
  const int tid = threadIdx.x;
  for (int e = tid; e < (CT + 2) * 16; e += 256) {
    int row = e >> 4, c16 = e & 15;
    int t = t0 + row;
    uint4 val = (t < LDIM) ? *(const uint4*)&X[(size_t)t * DDIM + c16 * 8]
                           : make_uint4(0u, 0u, 0u, 0u);
    int byte = row * 256 + ((c16 * 16) ^ ((row & 7) << 4));
    *(uint4*)((char*)Xs + byte) = val;
  }
  if (tid < FPAD) smax[tid] = 0.f;
  __syncthreads();
  const int w = tid >> 6, lane = tid & 63;
  const int lr = lane & 15, lg = lane >> 4;
  const int lt0 = w * 16;
  bf16x8 av[12];
  #pragma unroll
  for (int kk = 0; kk < 12; kk++) {
    int ko = kk * 4 + lg;          // k-octet 0..47; k = ko*8+e
    int ks = ko >> 4, d8 = ko & 15;
    int row = lt0 + lr + ks;
    int byte = row * 256 + ((d8 * 16) ^ ((row & 7) << 4));
    av[kk] = *(const bf16x8*)((const char*)Xs + byte);
  }
  for (int ft = 0; ft < 7; ft++) {
    f32x4 acc = {0.f, 0.f, 0.f, 0.f};
    #pragma unroll
    for (int kk = 0; kk < 12; kk++) {
      int ko = kk * 4 + lg;
      bf16x8 bv = *(const bf16x8*)&wB[((size_t)ko * FPAD + ft * 16 + lr) * 8];
      acc = __builtin_amdgcn_mfma_f32_16x16x32_bf16(av[kk], bv, acc, 0, 0, 0);
    }
    int f = ft * 16 + lr;
    float bb = (f < FDIM) ? bias[f] : 0.f;
    float mx = 0.f;
    #pragma unroll
    for (int r = 0; r < 4; r++) {
      int t = t0 + lt0 + lg * 4 + r;
      float y = fmaxf(acc[r] + bb, 0.f);
      if (t <= LDIM - 3) mx = fmaxf(mx, y);   // invalid t -> 0 (safe: relu-max >= 0)
    }
    mx = fmaxf(mx, __shfl_xor(mx, 16));
    mx = fmaxf(mx, __shfl_xor(mx, 32));
    if (lg == 0 && f < FDIM)
      atomicMax((unsigned*)&smax[f], __float_as_uint(mx));
  }
  __syncthreads();
  if (tid < FDIM)
    atomicMax((unsigned*)&out[(size_t)b * (2 * FDIM) + z * FDIM + tid],
              __float_as_uint(smax[tid]));
}

extern "C" void kernel_launch(void* const* d_in, const int* in_sizes, int n_in,
                              void* d_out, int out_size, void* d_ws, size_t ws_size,
                              hipStream_t stream) {
  const float* ctx   = (const float*)d_in[0];
  const float* mn    = (const float*)d_in[1];
  const float* wconv = (const float*)d_in[2];
  const float* bias  = (const float*)d_in[3];
  float* out = (float*)d_out;

  // pool accumulators must start at 0 (d_out is poisoned before every call)
  hipMemsetAsync(d_out, 0, sizeof(float)*(size_t)out_size, stream);

  // Workspace: [wB bf16 weight panel: 64K floats reserved] then per-iteration arrays.
  const size_t wbFloats = 65536;
  // Per-batch (floats/dwords):
  //   W (fp32):             L*L        = 4194304
  //   col partial records:  32*L*8     = 524288
  //   row partial records:   8*L*8     = 131072
  //   final stats:          14*L       = 28672
  //   attC:                 L*D        = 262144
  //   outCb+outMb (u16):    2*L*D u16  = 262144 float-equiv
  //   split-bf16 panels:    2*16*PANEL_U16/2 = 786432
  const size_t perBatchFloats = (size_t)LDIM*LDIM + (size_t)32*LDIM*8 + (size_t)8*LDIM*8
                              + 14*(size_t)LDIM + (size_t)LDIM*DDIM + (size_t)LDIM*DDIM
                              + 2*(size_t)16*PANEL_U16/2;
  const size_t perBatchBytes = perBatchFloats * sizeof(float);
  int nbMax = (int)((ws_size - wbFloats*sizeof(float)) / perBatchBytes);
  if (nbMax < 1) nbMax = 1;
  if (nbMax > BDIM) nbMax = BDIM;

  u16* wB = (u16*)d_ws;
  float* iterBase = (float*)d_ws + wbFloats;
  conv_prep_w<<<dim3((48*FPAD*8 + 255)/256), 256, 0, stream>>>(wconv, wB);

  for (int b0 = 0; b0 < BDIM; b0 += nbMax) {
    const int nb = (BDIM - b0 < nbMax) ? (BDIM - b0) : nbMax;
    float* Wbuf = iterBase;
    unsigned* colP = (unsigned*)(Wbuf + (size_t)nb*LDIM*LDIM);
    unsigned* rowP = colP + (size_t)nb*32*LDIM*8;
    float* rowW = (float*)(rowP + (size_t)nb*8*LDIM*8);
    int*   rowI = (int*)(rowW + (size_t)nb*LDIM*3);
    float* rowS = (float*)(rowI + (size_t)nb*LDIM*3);
    float* colW = rowS + (size_t)nb*LDIM;
    int*   colI = (int*)(colW + (size_t)nb*LDIM*3);
    float* colS = (float*)(colI + (size_t)nb*LDIM*3);
    float* attC = colS + (size_t)nb*LDIM;
    u16*   outCb = (u16*)(attC + (size_t)nb*LDIM*DDIM);
    u16*   outMb = outCb + (size_t)nb*LDIM*DDIM;
    u16*   ctxS = outMb + (size_t)nb*LDIM*DDIM;
    u16*   mnS  = ctxS + (size_t)nb*16*PANEL_U16;
    const float* ctxb = ctx + (size_t)b0*LDIM*DDIM;
    const float* mnb  = mn  + (size_t)b0*LDIM*DDIM;

    split_convert<<<dim3(128, nb), 256, 0, stream>>>(ctxb, mnb, ctxS, mnS);
    gemm_mfma<<<dim3(LDIM/128, LDIM/128, nb), 256, 0, stream>>>(ctxS, mnS, Wbuf);
    fused_stats<<<dim3(8, 32, nb), 256, 0, stream>>>(Wbuf, rowP, colP);
    stats_combine<<<dim3(LDIM/256, nb), 256, 0, stream>>>(rowP, 8, rowW, rowI, rowS);
    stats_combine<<<dim3(LDIM/256, nb), 256, 0, stream>>>(colP, 32, colW, colI, colS);
    hipMemsetAsync(attC, 0, (size_t)nb*LDIM*DDIM*sizeof(float), stream);
    scatter_att<<<dim3(LDIM, nb), 128, 0, stream>>>(ctxb, rowW, rowI, attC);
    make_outputs<<<dim3(LDIM, nb), 128, 0, stream>>>(ctxb, mnb, attC, rowS, colW, colI, colS, outCb, outMb);
    conv_mfma<<<dim3(LDIM/CT, nb, 2), 256, 0, stream>>>(
        outCb, outMb, wB, bias, out + (size_t)b0*2*FDIM);
  }
}

// Round 12
// 343.605 us; speedup vs baseline: 1.4619x; 1.3702x over previous
//
#include <hip/hip_runtime.h>
#include <math.h>

#define LDIM 2048
#define DDIM 128
#define BDIM 16
#define FDIM 100
// Split-K bf16 GEMM: A' = [AH | AL | AH], B' = [BH | BH | BL], K = 384.
// Panel layout per (batch,row-panel): [48 koct][128 row][8 elems] bf16 -> 16KB-contiguous K-tiles.
#define PANEL_U16 (48 * 1024)
// conv-as-GEMM: K = 3*128 = 384, N = 112 (100 filters padded to 7 tiles of 16)
#define FPAD 112
#define CT 64            // t-rows per conv block

typedef unsigned short u16;
typedef __bf16 bf16x8 __attribute__((ext_vector_type(8)));
typedef float f32x4 __attribute__((ext_vector_type(4)));

__device__ inline unsigned f2bfu(float x) {  // fp32 -> bf16 bits, RNE
  unsigned u = __float_as_uint(x);
  return (u + 0x7FFFu + ((u >> 16) & 1u)) >> 16;
}
__device__ inline unsigned pk2(float a, float b) {
  return f2bfu(a) | (f2bfu(b) << 16);
}
__device__ inline float bfhi(float x) {  // value of the bf16 hi part
  return __uint_as_float(f2bfu(x) << 16);
}

__device__ inline void glds16(const u16* g, u16* l) {
  __builtin_amdgcn_global_load_lds(
      (const __attribute__((address_space(1))) void*)g,
      (__attribute__((address_space(3))) void*)l, 16, 0, 0);
}

__device__ inline void ins3(float w, int idx, float v[3], int id[3]) {
  if (w > v[2]) {
    if (w > v[0]) { v[2]=v[1]; id[2]=id[1]; v[1]=v[0]; id[1]=id[0]; v[0]=w; id[0]=idx; }
    else if (w > v[1]) { v[2]=v[1]; id[2]=id[1]; v[1]=w; id[1]=idx; }
    else { v[2]=w; id[2]=idx; }
  }
}

// Expand fp32 inputs into split-bf16 panel layout (hi/lo), both ctx and main.
__global__ __launch_bounds__(256) void split_convert(const float* __restrict__ ctx,
    const float* __restrict__ mn, u16* __restrict__ ctxS, u16* __restrict__ mnS) {
  const int b = blockIdx.y;
  const int rp = blockIdx.x & 15, og = blockIdx.x >> 4;  // og 0..7
  const int tid = threadIdx.x;
  const int row = tid & 127;
  const int o = og * 2 + (tid >> 7);                     // source k-octet 0..15
  const size_t srcOff = (((size_t)b * LDIM + rp * 128 + row) * DDIM + o * 8);
  const float4 c0 = *(const float4*)(ctx + srcOff);
  const float4 c1 = *(const float4*)(ctx + srcOff + 4);
  const float4 m0 = *(const float4*)(mn + srcOff);
  const float4 m1 = *(const float4*)(mn + srcOff + 4);
  uint4 chi = make_uint4(pk2(c0.x,c0.y), pk2(c0.z,c0.w), pk2(c1.x,c1.y), pk2(c1.z,c1.w));
  uint4 clo = make_uint4(pk2(c0.x-bfhi(c0.x), c0.y-bfhi(c0.y)),
                         pk2(c0.z-bfhi(c0.z), c0.w-bfhi(c0.w)),
                         pk2(c1.x-bfhi(c1.x), c1.y-bfhi(c1.y)),
                         pk2(c1.z-bfhi(c1.z), c1.w-bfhi(c1.w)));
  uint4 mhi = make_uint4(pk2(m0.x,m0.y), pk2(m0.z,m0.w), pk2(m1.x,m1.y), pk2(m1.z,m1.w));
  uint4 mlo = make_uint4(pk2(m0.x-bfhi(m0.x), m0.y-bfhi(m0.y)),
                         pk2(m0.z-bfhi(m0.z), m0.w-bfhi(m0.w)),
                         pk2(m1.x-bfhi(m1.x), m1.y-bfhi(m1.y)),
                         pk2(m1.z-bfhi(m1.z), m1.w-bfhi(m1.w)));
  u16* dA = ctxS + ((size_t)b * 16 + rp) * PANEL_U16;
  u16* dB = mnS  + ((size_t)b * 16 + rp) * PANEL_U16;
  const int base = o * 1024 + row * 8;
  *(uint4*)(dA + base)         = chi;   // koct o      : AH
  *(uint4*)(dA + base + 16384) = clo;   // koct o + 16 : AL
  *(uint4*)(dA + base + 32768) = chi;   // koct o + 32 : AH
  *(uint4*)(dB + base)         = mhi;   // koct o      : BH
  *(uint4*)(dB + base + 16384) = mhi;   // koct o + 16 : BH
  *(uint4*)(dB + base + 32768) = mlo;   // koct o + 32 : BL
}

// W[b][c][m] = ctx.main^T via split-bf16 MFMA (K=384). W is NEVER stored.
// Epilogue: each 64x64 wave-quadrant is staged to a 64x65-padded LDS buffer
// (overlaid on dead As/Bs; 2 buffers, 2 rounds), then reduced by whole waves:
// wave0=cols/buf0, wave1=rows/buf0, wave2=cols/buf1, wave3=rows/buf1.
// Serial walks, no shuffles (R11-proven idiom); partial records in R8 format.
__global__ __launch_bounds__(256) void gemm_mfma(const u16* __restrict__ A,
    const u16* __restrict__ B, unsigned* __restrict__ rowP,
    unsigned* __restrict__ colP) {
  __shared__ __attribute__((aligned(16))) char ldsbuf[33280];
  u16* As = (u16*)ldsbuf;            // 16 KB (main loop)
  u16* Bs = As + 8192;               // 16 KB (main loop)
  float* stg = (float*)ldsbuf;       // epilogue: 2 x 4160 floats (64x65 each)
  const int b = blockIdx.z;
  const int rp = blockIdx.y, mp = blockIdx.x;
  const int tid = threadIdx.x;
  const int w = tid >> 6, lane = tid & 63;
  const int lr = lane & 15, lg = lane >> 4;
  const int wr = w >> 1, wc = w & 1;
  const u16* srcA = A + ((size_t)b * 16 + rp) * PANEL_U16;
  const u16* srcB = B + ((size_t)b * 16 + mp) * PANEL_U16;
  f32x4 acc[4][4];
  const f32x4 zz = {0.f, 0.f, 0.f, 0.f};
  #pragma unroll
  for (int i = 0; i < 4; i++)
    #pragma unroll
    for (int j = 0; j < 4; j++) acc[i][j] = zz;

  for (int kt = 0; kt < 6; kt++) {
    if (kt) __syncthreads();
    const u16* sA = srcA + kt * 8192;
    const u16* sB = srcB + kt * 8192;
    #pragma unroll
    for (int q = 0; q < 4; q++) {
      const int c = q * 256 + w * 64;           // chunk index base for this wave
      glds16(sA + (size_t)(c + lane) * 8, As + c * 8);
      glds16(sB + (size_t)(c + lane) * 8, Bs + c * 8);
    }
    __syncthreads();
    #pragma unroll
    for (int ks = 0; ks < 2; ks++) {
      const int ab = (ks * 4 + lg) * 1024 + (wr * 64 + lr) * 8;
      const int bb = (ks * 4 + lg) * 1024 + (wc * 64 + lr) * 8;
      bf16x8 av[4], bv[4];
      #pragma unroll
      for (int i = 0; i < 4; i++) av[i] = *(const bf16x8*)&As[ab + i * 128];
      #pragma unroll
      for (int j = 0; j < 4; j++) bv[j] = *(const bf16x8*)&Bs[bb + j * 128];
      #pragma unroll
      for (int i = 0; i < 4; i++)
        #pragma unroll
        for (int j = 0; j < 4; j++)
          acc[i][j] = __builtin_amdgcn_mfma_f32_16x16x32_bf16(av[i], bv[j], acc[i][j], 0, 0, 0);
    }
  }

  // ---- fused stats epilogue. C/D layout (m89, verified by R1 W-store):
  //      local row = i*16 + lg*4 + r, local col = j*16 + lr (within 64x64 quadrant).
  for (int rnd = 0; rnd < 2; rnd++) {
    __syncthreads();                       // As/Bs (or prev round stg) dead
    if (wr == rnd) {
      float* st = stg + wc * 4160;
      #pragma unroll
      for (int i = 0; i < 4; i++)
        #pragma unroll
        for (int r = 0; r < 4; r++) {
          const int row = i * 16 + lg * 4 + r;
          #pragma unroll
          for (int j = 0; j < 4; j++)
            st[row * 65 + j * 16 + lr] = acc[i][j][r];
        }
    }
    __syncthreads();
    {
      const int buf = tid >> 7;            // which staging buffer (== wc)
      const int role = (tid >> 6) & 1;     // 0: col reduce, 1: row reduce
      const int l6 = tid & 63;
      const float* st = stg + buf * 4160;
      float v[3] = {-3e38f,-3e38f,-3e38f}; int id[3] = {-1,-1,-1};
      float sm = 0.f, s2 = 0.f;
      if (role == 0) {
        // column l6 of this quadrant, over its 64 rows
        #pragma unroll 8
        for (int r = 0; r < 64; r++) {
          float wv = st[r * 65 + l6];
          sm += wv; s2 += wv*wv; ins3(wv, rp*128 + rnd*64 + r, v, id);
        }
        size_t rec = (((size_t)b*32 + rp*2 + rnd)*LDIM + mp*128 + buf*64 + l6) * 8;
        uint4 lo = make_uint4(__float_as_uint(v[0]), __float_as_uint(v[1]),
                              __float_as_uint(v[2]), __float_as_uint(sm));
        uint4 hi = make_uint4(__float_as_uint(s2), (unsigned)id[0],
                              (unsigned)id[1], (unsigned)id[2]);
        *(uint4*)(colP + rec)     = lo;
        *(uint4*)(colP + rec + 4) = hi;
      } else {
        // row l6 of this quadrant, over its 64 cols
        #pragma unroll 8
        for (int c = 0; c < 64; c++) {
          float wv = st[l6 * 65 + c];
          sm += wv; s2 += wv*wv; ins3(wv, mp*128 + buf*64 + c, v, id);
        }
        size_t rec = (((size_t)b*32 + mp*2 + buf)*LDIM + rp*128 + rnd*64 + l6) * 8;
        uint4 lo = make_uint4(__float_as_uint(v[0]), __float_as_uint(v[1]),
                              __float_as_uint(v[2]), __float_as_uint(sm));
        uint4 hi = make_uint4(__float_as_uint(s2), (unsigned)id[0],
                              (unsigned)id[1], (unsigned)id[2]);
        *(uint4*)(rowP + rec)     = lo;
        *(uint4*)(rowP + rec + 4) = hi;
      }
    }
  }
}

// Merge nt per-tile partials per index -> normalized top-3 weights + indices + std.
__global__ __launch_bounds__(256) void stats_combine(const unsigned* __restrict__ P,
    int nt, float* __restrict__ w3, int* __restrict__ i3, float* __restrict__ sd) {
  const int b = blockIdx.y;
  const int c = blockIdx.x * 256 + threadIdx.x;
  float v[3] = {-3e38f,-3e38f,-3e38f}; int id[3] = {-1,-1,-1};
  float sum = 0.f, sq = 0.f;
  for (int t = 0; t < nt; t++) {
    const unsigned* rec = P + (((size_t)b*nt + t)*LDIM + c) * 8;
    const uint4 lo = *(const uint4*)rec;
    const uint4 hi = *(const uint4*)(rec + 4);
    ins3(__uint_as_float(lo.x), (int)hi.y, v, id);
    ins3(__uint_as_float(lo.y), (int)hi.z, v, id);
    ins3(__uint_as_float(lo.z), (int)hi.w, v, id);
    sum += __uint_as_float(lo.w); sq += __uint_as_float(hi.x);
  }
  float inv = 1.f/(v[0]+v[1]+v[2]);
  size_t o = (size_t)b*LDIM + c;
  w3[o*3+0]=v[0]*inv; w3[o*3+1]=v[1]*inv; w3[o*3+2]=v[2]*inv;
  i3[o*3+0]=id[0]; i3[o*3+1]=id[1]; i3[o*3+2]=id[2];
  float mean = sum * (1.f/LDIM);
  float var = sq*(1.f/LDIM) - mean*mean;
  sd[o] = sqrtf(fmaxf(var, 0.f));
}

// att_merge_c[m][d] += wk_c[c][m] * ctx[c][d]  -- 3 targets per row c (scatter).
__global__ __launch_bounds__(128) void scatter_att(const float* __restrict__ ctx,
    const float* __restrict__ rw, const int* __restrict__ ri,
    float* __restrict__ attC) {
  const int b = blockIdx.y, c = blockIdx.x, d = threadIdx.x;
  const size_t base = (size_t)b*LDIM + c;
  const float x = ctx[base*DDIM + d];
  #pragma unroll
  for (int t = 0; t < 3; t++) {
    float w = rw[base*3 + t];
    int m = ri[base*3 + t];
    atomicAdd(&attC[((size_t)b*LDIM + m)*DDIM + d], w*x);
  }
}

// outputs_c = |ctx - gather(col top-3 of main)| * row_std   -> bf16
// outputs_m = |main - attC| * col_std                       -> bf16
__global__ __launch_bounds__(128) void make_outputs(const float* __restrict__ ctx,
    const float* __restrict__ mn, const float* __restrict__ attC,
    const float* __restrict__ rs, const float* __restrict__ cw,
    const int* __restrict__ ci, const float* __restrict__ cs,
    u16* __restrict__ outCb, u16* __restrict__ outMb) {
  const int b = blockIdx.y, i = blockIdx.x, d = threadIdx.x;
  const size_t base = (size_t)b*LDIM + i;
  float am = 0.f;
  #pragma unroll
  for (int t = 0; t < 3; t++)
    am += cw[base*3+t] * mn[((size_t)b*LDIM + ci[base*3+t])*DDIM + d];
  float oc = fabsf(ctx[base*DDIM + d] - am) * rs[base];
  float om = fabsf(mn[base*DDIM + d] - attC[base*DDIM + d]) * cs[base];
  outCb[base*DDIM + d] = (u16)f2bfu(oc);
  outMb[base*DDIM + d] = (u16)f2bfu(om);
}

// Convert conv weights to bf16 panel wB[ko 0..47][f 0..111][e 0..7]:
// wB[ko][f][e] = w[ks = ko/16][d = (ko%16)*8 + e][f], f >= FDIM -> 0.
__global__ __launch_bounds__(256) void conv_prep_w(const float* __restrict__ wv,
    u16* __restrict__ wB) {
  int idx = blockIdx.x * 256 + threadIdx.x;
  if (idx >= 48 * FPAD * 8) return;
  int e = idx & 7, f = (idx >> 3) % FPAD, ko = idx / (FPAD * 8);
  int ks = ko >> 4, d = ((ko & 15) << 3) | e;
  float val = (f < FDIM) ? wv[(ks * DDIM + d) * FDIM + f] : 0.f;
  wB[idx] = (u16)f2bfu(val);
}

// conv1d(KS=3) + bias + relu + maxpool as MFMA GEMM: y[t,f] = sum_k X[t+ks,d]*w[ks,d,f].
// Block: 256 thr = 4 waves, covers CT=64 t-rows x all 112 f. K=384 -> 12 MFMA/f-tile.
__global__ __launch_bounds__(256) void conv_mfma(const u16* __restrict__ XCb,
    const u16* __restrict__ XMb, const u16* __restrict__ wB,
    const float* __restrict__ bias, float* __restrict__ out) {
  const int b = blockIdx.y, z = blockIdx.z;
  const int t0 = blockIdx.x * CT;
  const u16* X = (z == 0 ? XCb : XMb) + (size_t)b * LDIM * DDIM;
  __shared__ u16 Xs[(CT + 2) * 128];   // rows of 256B, XOR-swizzled
  __shared__ float smax[FPAD];
  const int tid = threadIdx.x;
  for (int e = tid; e < (CT + 2) * 16; e += 256) {
    int row = e >> 4, c16 = e & 15;
    int t = t0 + row;
    uint4 val = (t < LDIM) ? *(const uint4*)&X[(size_t)t * DDIM + c16 * 8]
                           : make_uint4(0u, 0u, 0u, 0u);
    int byte = row * 256 + ((c16 * 16) ^ ((row & 7) << 4));
    *(uint4*)((char*)Xs + byte) = val;
  }
  if (tid < FPAD) smax[tid] = 0.f;
  __syncthreads();
  const int w = tid >> 6, lane = tid & 63;
  const int lr = lane & 15, lg = lane >> 4;
  const int lt0 = w * 16;
  bf16x8 av[12];
  #pragma unroll
  for (int kk = 0; kk < 12; kk++) {
    int ko = kk * 4 + lg;          // k-octet 0..47; k = ko*8+e
    int ks = ko >> 4, d8 = ko & 15;
    int row = lt0 + lr + ks;
    int byte = row * 256 + ((d8 * 16) ^ ((row & 7) << 4));
    av[kk] = *(const bf16x8*)((const char*)Xs + byte);
  }
  for (int ft = 0; ft < 7; ft++) {
    f32x4 acc = {0.f, 0.f, 0.f, 0.f};
    #pragma unroll
    for (int kk = 0; kk < 12; kk++) {
      int ko = kk * 4 + lg;
      bf16x8 bv = *(const bf16x8*)&wB[((size_t)ko * FPAD + ft * 16 + lr) * 8];
      acc = __builtin_amdgcn_mfma_f32_16x16x32_bf16(av[kk], bv, acc, 0, 0, 0);
    }
    int f = ft * 16 + lr;
    float bb = (f < FDIM) ? bias[f] : 0.f;
    float mx = 0.f;
    #pragma unroll
    for (int r = 0; r < 4; r++) {
      int t = t0 + lt0 + lg * 4 + r;
      float y = fmaxf(acc[r] + bb, 0.f);
      if (t <= LDIM - 3) mx = fmaxf(mx, y);   // invalid t -> 0 (safe: relu-max >= 0)
    }
    mx = fmaxf(mx, __shfl_xor(mx, 16));
    mx = fmaxf(mx, __shfl_xor(mx, 32));
    if (lg == 0 && f < FDIM)
      atomicMax((unsigned*)&smax[f], __float_as_uint(mx));
  }
  __syncthreads();
  if (tid < FDIM)
    atomicMax((unsigned*)&out[(size_t)b * (2 * FDIM) + z * FDIM + tid],
              __float_as_uint(smax[tid]));
}

extern "C" void kernel_launch(void* const* d_in, const int* in_sizes, int n_in,
                              void* d_out, int out_size, void* d_ws, size_t ws_size,
                              hipStream_t stream) {
  const float* ctx   = (const float*)d_in[0];
  const float* mn    = (const float*)d_in[1];
  const float* wconv = (const float*)d_in[2];
  const float* bias  = (const float*)d_in[3];
  float* out = (float*)d_out;

  // pool accumulators must start at 0 (d_out is poisoned before every call)
  hipMemsetAsync(d_out, 0, sizeof(float)*(size_t)out_size, stream);

  // Workspace: [wB bf16 weight panel: 64K floats reserved] then per-iteration arrays.
  const size_t wbFloats = 65536;
  // Per-batch (floats/dwords) -- W is GONE:
  //   row partial records:  32*L*8     = 524288
  //   col partial records:  32*L*8     = 524288
  //   final stats:          14*L       = 28672
  //   attC:                 L*D        = 262144
  //   outCb+outMb (u16):    2*L*D u16  = 262144 float-equiv
  //   split-bf16 panels:    2*16*PANEL_U16/2 = 786432
  const size_t perBatchFloats = (size_t)32*LDIM*8 + (size_t)32*LDIM*8
                              + 14*(size_t)LDIM + (size_t)LDIM*DDIM + (size_t)LDIM*DDIM
                              + 2*(size_t)16*PANEL_U16/2;
  const size_t perBatchBytes = perBatchFloats * sizeof(float);
  int nbMax = (int)((ws_size - wbFloats*sizeof(float)) / perBatchBytes);
  if (nbMax < 1) nbMax = 1;
  if (nbMax > BDIM) nbMax = BDIM;

  u16* wB = (u16*)d_ws;
  float* iterBase = (float*)d_ws + wbFloats;
  conv_prep_w<<<dim3((48*FPAD*8 + 255)/256), 256, 0, stream>>>(wconv, wB);

  for (int b0 = 0; b0 < BDIM; b0 += nbMax) {
    const int nb = (BDIM - b0 < nbMax) ? (BDIM - b0) : nbMax;
    unsigned* rowP = (unsigned*)iterBase;
    unsigned* colP = rowP + (size_t)nb*32*LDIM*8;
    float* rowW = (float*)(colP + (size_t)nb*32*LDIM*8);
    int*   rowI = (int*)(rowW + (size_t)nb*LDIM*3);
    float* rowS = (float*)(rowI + (size_t)nb*LDIM*3);
    float* colW = rowS + (size_t)nb*LDIM;
    int*   colI = (int*)(colW + (size_t)nb*LDIM*3);
    float* colS = (float*)(colI + (size_t)nb*LDIM*3);
    float* attC = colS + (size_t)nb*LDIM;
    u16*   outCb = (u16*)(attC + (size_t)nb*LDIM*DDIM);
    u16*   outMb = outCb + (size_t)nb*LDIM*DDIM;
    u16*   ctxS = outMb + (size_t)nb*LDIM*DDIM;
    u16*   mnS  = ctxS + (size_t)nb*16*PANEL_U16;
    const float* ctxb = ctx + (size_t)b0*LDIM*DDIM;
    const float* mnb  = mn  + (size_t)b0*LDIM*DDIM;

    split_convert<<<dim3(128, nb), 256, 0, stream>>>(ctxb, mnb, ctxS, mnS);
    gemm_mfma<<<dim3(LDIM/128, LDIM/128, nb), 256, 0, stream>>>(
        ctxS, mnS, rowP, colP);
    stats_combine<<<dim3(LDIM/256, nb), 256, 0, stream>>>(rowP, 32, rowW, rowI, rowS);
    stats_combine<<<dim3(LDIM/256, nb), 256, 0, stream>>>(colP, 32, colW, colI, colS);
    hipMemsetAsync(attC, 0, (size_t)nb*LDIM*DDIM*sizeof(float), stream);
    scatter_att<<<dim3(LDIM, nb), 128, 0, stream>>>(ctxb, rowW, rowI, attC);
    make_outputs<<<dim3(LDIM, nb), 128, 0, stream>>>(ctxb, mnb, attC, rowS, colW, colI, colS, outCb, outMb);
    conv_mfma<<<dim3(LDIM/CT, nb, 2), 256, 0, stream>>>(
        outCb, outMb, wB, bias, out + (size_t)b0*2*FDIM);
  }
}